// Round 3
// baseline (297.741 us; speedup 1.0000x reference)
//
#include <hip/hip_runtime.h>
#include <hip/hip_bf16.h>

#define DEVI __device__ __forceinline__

typedef float f32x4 __attribute__((ext_vector_type(4)));
typedef short bf16x8 __attribute__((ext_vector_type(8)));
typedef int i32x4 __attribute__((ext_vector_type(4)));

constexpr int BATCH = 4;
constexpr int SEQ   = 2048;
constexpr int DIM   = 1024;
constexpr int NH    = 16;
constexpr int HD    = 64;
constexpr int TD    = 3 * DIM;       // 3072
constexpr int MTOT  = BATCH * SEQ;   // 8192

// 1/sqrt(64) * log2(e), folded into Q at the QKV-GEMM epilogue.
constexpr float QSCALE = 0.125f * 1.44269504f;

DEVI unsigned short f2bf(float f) {
    __hip_bfloat16 h = __float2bfloat16(f);   // native cvt, RNE
    return *reinterpret_cast<unsigned short*>(&h);
}

DEVI void gload_lds16(const unsigned short* gsrc, unsigned short* ldst) {
    __builtin_amdgcn_global_load_lds(
        (const __attribute__((address_space(1))) void*)gsrc,
        (__attribute__((address_space(3))) void*)ldst,
        16, 0, 0);
}

// ---------------- convert f32 -> bf16 ----------------
__global__ void cvt_kernel(const float* __restrict__ in, unsigned short* __restrict__ out, int n4) {
    int i = blockIdx.x * blockDim.x + threadIdx.x;
    int stride = gridDim.x * blockDim.x;
    for (; i < n4; i += stride) {
        float4 v = reinterpret_cast<const float4*>(in)[i];
        ushort4 o;
        o.x = f2bf(v.x); o.y = f2bf(v.y); o.z = f2bf(v.z); o.w = f2bf(v.w);
        reinterpret_cast<ushort4*>(out)[i] = o;
    }
}

// ---------------- transpose f32 [R][C] -> bf16 [C][R] ----------------
__global__ void transp_kernel(const float* __restrict__ in, unsigned short* __restrict__ out, int R, int C) {
    __shared__ float tile[32][33];
    int c0 = blockIdx.x * 32, r0 = blockIdx.y * 32;
    int tx = threadIdx.x, ty = threadIdx.y;  // block 32x8
#pragma unroll
    for (int i = 0; i < 32; i += 8)
        tile[ty + i][tx] = in[(long)(r0 + ty + i) * C + c0 + tx];
    __syncthreads();
#pragma unroll
    for (int i = 0; i < 32; i += 8)
        out[(long)(c0 + ty + i) * R + r0 + tx] = f2bf(tile[tx][ty + i]);
}

// ---------------- GEMM: C[M][N] = A[M][K] * Bt[N][K]^T + bias ----------------
// m97 structure: 128x128 tile, BK=32, 4 waves (each 64x64), global_load_lds w=16.
// Columns [0, scale_ncols) of the output are multiplied by scl (fp32, pre-round)
// -- used to fold the attention score scale into Q for free.
template <bool OUT_BF16>
__global__ __launch_bounds__(256) void gemm_bt_kernel(
    const unsigned short* __restrict__ A,   // [M][K] bf16
    const unsigned short* __restrict__ Bt,  // [N][K] bf16
    const float* __restrict__ bias,         // [N]
    void* __restrict__ Cout,
    int M, int Nn, int K, int scale_ncols, float scl)
{
    __shared__ unsigned short As[128 * 32];
    __shared__ unsigned short Bs[128 * 32];

    const int t  = threadIdx.x;
    const int l  = t & 63;
    const int w  = t >> 6;
    const int wr = w >> 1, wc = w & 1;
    const int tr = blockIdx.y, tc = blockIdx.x;
    const int lrow = l & 15, lk = l >> 4;

    f32x4 acc[4][4] = {};

    const int r0  = t >> 2;
    const int ch0 = t & 3;
    const long arow_base = (long)(tr * 128) * K;
    const long brow_base = (long)(tc * 128) * K;

    const int nk = K >> 5;
    for (int kt = 0; kt < nk; ++kt) {
        const int kb = kt * 32;
        gload_lds16(A  + arow_base + (long)r0 * K        + kb + ch0 * 8, &As[t * 8]);
        gload_lds16(A  + arow_base + (long)(r0 + 64) * K + kb + ch0 * 8, &As[(t + 256) * 8]);
        gload_lds16(Bt + brow_base + (long)r0 * K        + kb + ch0 * 8, &Bs[t * 8]);
        gload_lds16(Bt + brow_base + (long)(r0 + 64) * K + kb + ch0 * 8, &Bs[(t + 256) * 8]);
        __syncthreads();

        bf16x8 a[4], bb[4];
#pragma unroll
        for (int mi = 0; mi < 4; ++mi)
            a[mi] = *(const bf16x8*)&As[(wr * 64 + mi * 16 + lrow) * 32 + lk * 8];
#pragma unroll
        for (int ni = 0; ni < 4; ++ni)
            bb[ni] = *(const bf16x8*)&Bs[(wc * 64 + ni * 16 + lrow) * 32 + lk * 8];
#pragma unroll
        for (int mi = 0; mi < 4; ++mi)
#pragma unroll
            for (int ni = 0; ni < 4; ++ni)
                acc[mi][ni] = __builtin_amdgcn_mfma_f32_16x16x32_bf16(a[mi], bb[ni], acc[mi][ni], 0, 0, 0);
        __syncthreads();
    }

    const int row_base = tr * 128 + wr * 64;
    const int col_base = tc * 128 + wc * 64;
    const float mult = (col_base < scale_ncols) ? scl : 1.0f;  // uniform per block (128 | DIM)
    float bv[4];
#pragma unroll
    for (int ni = 0; ni < 4; ++ni) bv[ni] = bias[col_base + ni * 16 + lrow];

#pragma unroll
    for (int mi = 0; mi < 4; ++mi)
#pragma unroll
        for (int ni = 0; ni < 4; ++ni)
#pragma unroll
            for (int r = 0; r < 4; ++r) {
                int row = row_base + mi * 16 + lk * 4 + r;
                int col = col_base + ni * 16 + lrow;
                float v = (acc[mi][ni][r] + bv[ni]) * mult;
                if (OUT_BF16) ((unsigned short*)Cout)[(long)row * Nn + col] = f2bf(v);
                else          ((float*)Cout)[(long)row * Nn + col] = v;
            }
}

// ---------------- fused flash attention (swapped-operand, 2 q-sets/wave) ----
// block: 256 threads = 4 waves; each wave owns 32 q-rows (two 16-col B-sets);
// KV tiles of 64. S^T = mfma(K, Qset): lane holds key-slices of one q-column
// (q = set*16 + lane&15). K/V staging + Ks/VsT reads are shared by both sets.
// Q arrives pre-scaled by 0.125*log2e, so scores are already in log2 domain.
// Defer-max (T13, THR=8): skip O-rescale when no lane's max grew past mrun+8.
__global__ __launch_bounds__(256) void attn_kernel(
    const unsigned short* __restrict__ qkv,  // [MTOT][TD]; Q at h*64, K at 1024+h*64, V at 2048+h*64
    unsigned short* __restrict__ aout)       // [MTOT][DIM], col = h*64+d
{
    constexpr int KVB  = 64;
    constexpr int PADW = 72;
    __shared__ unsigned short Ks[KVB * PADW];       // [key][d]
    __shared__ unsigned short VsT[HD * PADW];       // [d][key]
    __shared__ unsigned short Plds[4 * 32 * PADW];  // per-wave [q(32)][key]

    const int t = threadIdx.x;
    const int l = t & 63;
    const int w = t >> 6;
    const int lrow = l & 15, lk = l >> 4;

    const int b  = blockIdx.y >> 4;
    const int h  = blockIdx.y & 15;
    const int q0 = blockIdx.x * 128 + w * 32;

    // Q fragments as B-operand, two q-sets (n = q = set*16 + lane&15)
    bf16x8 bq[2][2];
#pragma unroll
    for (int s = 0; s < 2; ++s) {
        const long qrow = (long)(b * SEQ + q0 + s * 16 + lrow) * TD + h * HD;
        bq[s][0] = *(const bf16x8*)&qkv[qrow + lk * 8];
        bq[s][1] = *(const bf16x8*)&qkv[qrow + 32 + lk * 8];
    }

    f32x4 o[2][4] = {};                  // O^T: lane q = set*16+lrow, d = 16*f2+4*lk+r
    float mrun[2] = { -1e30f, -1e30f };
    float lsum[2] = { 0.f, 0.f };

    const int vch = t >> 5, vrp = t & 31;
    const long kbase = (long)(b * SEQ) * TD + DIM + h * HD;
    const long vbase = (long)(b * SEQ) * TD + 2 * DIM + h * HD;

    unsigned short* P = &Plds[w * 32 * PADW];

    for (int m0 = 0; m0 < SEQ; m0 += KVB) {
        // ---- stage K tile [64][64] ----
#pragma unroll
        for (int i = 0; i < 2; ++i) {
            int c = t + i * 256;
            int row = c & 63, ch = c >> 6;
            i32x4 v = *(const i32x4*)&qkv[kbase + (long)(m0 + row) * TD + ch * 8];
            *(i32x4*)&Ks[row * PADW + ch * 8] = v;
        }
        // ---- stage V transposed [d][key], packed row-pairs ----
        {
            const unsigned short* s0p = &qkv[vbase + (long)(m0 + 2 * vrp) * TD + vch * 8];
            i32x4 v0 = *(const i32x4*)s0p;
            i32x4 v1 = *(const i32x4*)(s0p + TD);
            const unsigned short* u0 = (const unsigned short*)&v0;
            const unsigned short* u1 = (const unsigned short*)&v1;
            unsigned int* V32 = (unsigned int*)VsT;  // [d][36]
#pragma unroll
            for (int j = 0; j < 8; ++j) {
                unsigned int word = (unsigned int)u0[j] | ((unsigned int)u1[j] << 16);
                V32[(vch * 8 + j) * 36 + vrp] = word;
            }
        }
        __syncthreads();

        // ---- QK^T swapped, both q-sets share the K fragments ----
        f32x4 sv[2][4];
#pragma unroll
        for (int f = 0; f < 4; ++f) {
            bf16x8 ak0 = *(const bf16x8*)&Ks[(f * 16 + lrow) * PADW + lk * 8];
            bf16x8 ak1 = *(const bf16x8*)&Ks[(f * 16 + lrow) * PADW + 32 + lk * 8];
#pragma unroll
            for (int s = 0; s < 2; ++s) {
                f32x4 z = {};
                z = __builtin_amdgcn_mfma_f32_16x16x32_bf16(ak0, bq[s][0], z, 0, 0, 0);
                z = __builtin_amdgcn_mfma_f32_16x16x32_bf16(ak1, bq[s][1], z, 0, 0, 0);
                sv[s][f] = z;
            }
        }

        // ---- online softmax (scores already in log2 domain) ----
        float vmax[2];
#pragma unroll
        for (int s = 0; s < 2; ++s) {
            float a0 = fmaxf(fmaxf(sv[s][0][0], sv[s][0][1]), fmaxf(sv[s][0][2], sv[s][0][3]));
            float a1 = fmaxf(fmaxf(sv[s][1][0], sv[s][1][1]), fmaxf(sv[s][1][2], sv[s][1][3]));
            float a2 = fmaxf(fmaxf(sv[s][2][0], sv[s][2][1]), fmaxf(sv[s][2][2], sv[s][2][3]));
            float a3 = fmaxf(fmaxf(sv[s][3][0], sv[s][3][1]), fmaxf(sv[s][3][2], sv[s][3][3]));
            float vm = fmaxf(fmaxf(a0, a1), fmaxf(a2, a3));
            vm = fmaxf(vm, __shfl_xor(vm, 16));
            vm = fmaxf(vm, __shfl_xor(vm, 32));
            vmax[s] = vm;
        }

        // T13 defer-max: rescale only when some lane's max grew past mrun+8
        if (!__all(vmax[0] <= mrun[0] + 8.f && vmax[1] <= mrun[1] + 8.f)) {
#pragma unroll
            for (int s = 0; s < 2; ++s) {
                float mnew = fmaxf(mrun[s], vmax[s]);
                float sc = exp2f(mrun[s] - mnew);
                mrun[s] = mnew;
                lsum[s] *= sc;
#pragma unroll
                for (int f2 = 0; f2 < 4; ++f2)
#pragma unroll
                    for (int r = 0; r < 4; ++r) o[s][f2][r] *= sc;
            }
        }

#pragma unroll
        for (int s = 0; s < 2; ++s) {
            float ps = 0.f;
#pragma unroll
            for (int f = 0; f < 4; ++f)
#pragma unroll
                for (int r = 0; r < 4; ++r) {
                    float p = exp2f(sv[s][f][r] - mrun[s]);
                    sv[s][f][r] = p;
                    ps += p;
                }
            ps += __shfl_xor(ps, 16);
            ps += __shfl_xor(ps, 32);
            lsum[s] += ps;
        }

        // ---- P -> LDS as [q][key] rows (wave-private), packed 32-bit writes ----
#pragma unroll
        for (int s = 0; s < 2; ++s)
#pragma unroll
            for (int f = 0; f < 4; ++f)
#pragma unroll
                for (int rr = 0; rr < 2; ++rr) {
                    ushort2 wd;
                    wd.x = f2bf(sv[s][f][2 * rr]);
                    wd.y = f2bf(sv[s][f][2 * rr + 1]);
                    *(ushort2*)&P[(s * 16 + lrow) * PADW + f * 16 + lk * 4 + 2 * rr] = wd;
                }

        // ---- PV transposed: O^T += V^T[d][k] * P^T[k][q], V frags shared ----
        bf16x8 pb[2][2];
#pragma unroll
        for (int s = 0; s < 2; ++s) {
            pb[s][0] = *(const bf16x8*)&P[(s * 16 + lrow) * PADW + lk * 8];
            pb[s][1] = *(const bf16x8*)&P[(s * 16 + lrow) * PADW + 32 + lk * 8];
        }
#pragma unroll
        for (int f2 = 0; f2 < 4; ++f2) {
            bf16x8 av0 = *(const bf16x8*)&VsT[(f2 * 16 + lrow) * PADW + lk * 8];
            bf16x8 av1 = *(const bf16x8*)&VsT[(f2 * 16 + lrow) * PADW + 32 + lk * 8];
#pragma unroll
            for (int s = 0; s < 2; ++s) {
                o[s][f2] = __builtin_amdgcn_mfma_f32_16x16x32_bf16(av0, pb[s][0], o[s][f2], 0, 0, 0);
                o[s][f2] = __builtin_amdgcn_mfma_f32_16x16x32_bf16(av1, pb[s][1], o[s][f2], 0, 0, 0);
            }
        }
        __syncthreads();
    }

    // ---- normalize + store ----
#pragma unroll
    for (int s = 0; s < 2; ++s) {
        float inv = 1.0f / lsum[s];
        const long orow = (long)(b * SEQ + q0 + s * 16 + lrow);
#pragma unroll
        for (int f2 = 0; f2 < 4; ++f2) {
            ushort4 st;
            st.x = f2bf(o[s][f2][0] * inv);
            st.y = f2bf(o[s][f2][1] * inv);
            st.z = f2bf(o[s][f2][2] * inv);
            st.w = f2bf(o[s][f2][3] * inv);
            *(ushort4*)&aout[orow * DIM + h * HD + f2 * 16 + lk * 4] = st;
        }
    }
}

extern "C" void kernel_launch(void* const* d_in, const int* in_sizes, int n_in,
                              void* d_out, int out_size, void* d_ws, size_t ws_size,
                              hipStream_t stream)
{
    const float* x      = (const float*)d_in[0];
    const float* w_qkv  = (const float*)d_in[1];
    const float* b_qkv  = (const float*)d_in[2];
    const float* w_proj = (const float*)d_in[3];
    const float* b_proj = (const float*)d_in[4];
    float* out = (float*)d_out;

    unsigned short* x_bf   = (unsigned short*)d_ws;                 // 8192*1024
    unsigned short* wqkvT  = x_bf   + (size_t)MTOT * DIM;           // [3072][1024]
    unsigned short* wprojT = wqkvT  + (size_t)TD * DIM;             // [1024][1024]
    unsigned short* qkv    = wprojT + (size_t)DIM * DIM;            // [8192][3072]
    unsigned short* attn   = qkv    + (size_t)MTOT * TD;            // [8192][1024]

    cvt_kernel<<<2048, 256, 0, stream>>>(x, x_bf, MTOT * DIM / 4);
    dim3 tb(32, 8);
    transp_kernel<<<dim3(TD / 32, DIM / 32), tb, 0, stream>>>(w_qkv, wqkvT, DIM, TD);
    transp_kernel<<<dim3(DIM / 32, DIM / 32), tb, 0, stream>>>(w_proj, wprojT, DIM, DIM);

    // Q columns pre-scaled by 0.125*log2e (fp32, before bf16 round)
    gemm_bt_kernel<true><<<dim3(TD / 128, MTOT / 128), 256, 0, stream>>>(
        x_bf, wqkvT, b_qkv, qkv, MTOT, TD, DIM, DIM, QSCALE);

    attn_kernel<<<dim3(SEQ / 128, BATCH * NH), 256, 0, stream>>>(qkv, attn);

    gemm_bt_kernel<false><<<dim3(DIM / 128, MTOT / 128), 256, 0, stream>>>(
        attn, wprojT, b_proj, out, MTOT, DIM, DIM, 0, 1.0f);
}

// Round 4
// 262.409 us; speedup vs baseline: 1.1346x; 1.1346x over previous
//
#include <hip/hip_runtime.h>
#include <hip/hip_bf16.h>

#define DEVI __device__ __forceinline__

typedef float f32x4 __attribute__((ext_vector_type(4)));
typedef short bf16x8 __attribute__((ext_vector_type(8)));
typedef int i32x4 __attribute__((ext_vector_type(4)));

constexpr int BATCH = 4;
constexpr int SEQ   = 2048;
constexpr int DIM   = 1024;
constexpr int NH    = 16;
constexpr int HD    = 64;
constexpr int TD    = 3 * DIM;       // 3072
constexpr int MTOT  = BATCH * SEQ;   // 8192

// 1/sqrt(64) * log2(e), folded into Q at the QKV-GEMM epilogue.
constexpr float QSCALE = 0.125f * 1.44269504f;

DEVI unsigned short f2bf(float f) {
    __hip_bfloat16 h = __float2bfloat16(f);   // native cvt, RNE
    return *reinterpret_cast<unsigned short*>(&h);
}

DEVI void gload_lds16(const unsigned short* gsrc, unsigned short* ldst) {
    __builtin_amdgcn_global_load_lds(
        (const __attribute__((address_space(1))) void*)gsrc,
        (__attribute__((address_space(3))) void*)ldst,
        16, 0, 0);
}

// ---------------- convert f32 -> bf16 ----------------
__global__ void cvt_kernel(const float* __restrict__ in, unsigned short* __restrict__ out, int n4) {
    int i = blockIdx.x * blockDim.x + threadIdx.x;
    int stride = gridDim.x * blockDim.x;
    for (; i < n4; i += stride) {
        float4 v = reinterpret_cast<const float4*>(in)[i];
        ushort4 o;
        o.x = f2bf(v.x); o.y = f2bf(v.y); o.z = f2bf(v.z); o.w = f2bf(v.w);
        reinterpret_cast<ushort4*>(out)[i] = o;
    }
}

// ---------------- transpose f32 [R][C] -> bf16 [C][R] ----------------
__global__ void transp_kernel(const float* __restrict__ in, unsigned short* __restrict__ out, int R, int C) {
    __shared__ float tile[32][33];
    int c0 = blockIdx.x * 32, r0 = blockIdx.y * 32;
    int tx = threadIdx.x, ty = threadIdx.y;  // block 32x8
#pragma unroll
    for (int i = 0; i < 32; i += 8)
        tile[ty + i][tx] = in[(long)(r0 + ty + i) * C + c0 + tx];
    __syncthreads();
#pragma unroll
    for (int i = 0; i < 32; i += 8)
        out[(long)(c0 + ty + i) * R + r0 + tx] = f2bf(tile[tx][ty + i]);
}

// ---------------- GEMM: C[M][N] = A[M][K] * Bt[N][K]^T + bias ----------------
// m97 structure: 128x128 tile, BK=32, 4 waves (each 64x64), global_load_lds w=16.
// Columns [0, scale_ncols) of the output are multiplied by scl (fp32, pre-round).
template <bool OUT_BF16>
__global__ __launch_bounds__(256) void gemm_bt_kernel(
    const unsigned short* __restrict__ A,   // [M][K] bf16
    const unsigned short* __restrict__ Bt,  // [N][K] bf16
    const float* __restrict__ bias,         // [N]
    void* __restrict__ Cout,
    int M, int Nn, int K, int scale_ncols, float scl)
{
    __shared__ unsigned short As[128 * 32];
    __shared__ unsigned short Bs[128 * 32];

    const int t  = threadIdx.x;
    const int l  = t & 63;
    const int w  = t >> 6;
    const int wr = w >> 1, wc = w & 1;
    const int tr = blockIdx.y, tc = blockIdx.x;
    const int lrow = l & 15, lk = l >> 4;

    f32x4 acc[4][4] = {};

    const int r0  = t >> 2;
    const int ch0 = t & 3;
    const long arow_base = (long)(tr * 128) * K;
    const long brow_base = (long)(tc * 128) * K;

    const int nk = K >> 5;
    for (int kt = 0; kt < nk; ++kt) {
        const int kb = kt * 32;
        gload_lds16(A  + arow_base + (long)r0 * K        + kb + ch0 * 8, &As[t * 8]);
        gload_lds16(A  + arow_base + (long)(r0 + 64) * K + kb + ch0 * 8, &As[(t + 256) * 8]);
        gload_lds16(Bt + brow_base + (long)r0 * K        + kb + ch0 * 8, &Bs[t * 8]);
        gload_lds16(Bt + brow_base + (long)(r0 + 64) * K + kb + ch0 * 8, &Bs[(t + 256) * 8]);
        __syncthreads();

        bf16x8 a[4], bb[4];
#pragma unroll
        for (int mi = 0; mi < 4; ++mi)
            a[mi] = *(const bf16x8*)&As[(wr * 64 + mi * 16 + lrow) * 32 + lk * 8];
#pragma unroll
        for (int ni = 0; ni < 4; ++ni)
            bb[ni] = *(const bf16x8*)&Bs[(wc * 64 + ni * 16 + lrow) * 32 + lk * 8];
#pragma unroll
        for (int mi = 0; mi < 4; ++mi)
#pragma unroll
            for (int ni = 0; ni < 4; ++ni)
                acc[mi][ni] = __builtin_amdgcn_mfma_f32_16x16x32_bf16(a[mi], bb[ni], acc[mi][ni], 0, 0, 0);
        __syncthreads();
    }

    const int row_base = tr * 128 + wr * 64;
    const int col_base = tc * 128 + wc * 64;
    const float mult = (col_base < scale_ncols) ? scl : 1.0f;  // uniform per block (128 | DIM)
    float bv[4];
#pragma unroll
    for (int ni = 0; ni < 4; ++ni) bv[ni] = bias[col_base + ni * 16 + lrow];

#pragma unroll
    for (int mi = 0; mi < 4; ++mi)
#pragma unroll
        for (int ni = 0; ni < 4; ++ni)
#pragma unroll
            for (int r = 0; r < 4; ++r) {
                int row = row_base + mi * 16 + lk * 4 + r;
                int col = col_base + ni * 16 + lrow;
                float v = (acc[mi][ni][r] + bv[ni]) * mult;
                if (OUT_BF16) ((unsigned short*)Cout)[(long)row * Nn + col] = f2bf(v);
                else          ((float*)Cout)[(long)row * Nn + col] = v;
            }
}

// ---------------- fused flash attention ----------------
// Swapped-operand form, 2 q-sets/wave (32 q-rows), KV tiles of 64.
// T14 async-STAGE: tile t+1's K/V are global-loaded into REGISTERS before
// tile t's compute, and committed to LDS only after the end-of-tile barrier
// -- HBM latency hides under QK^T/softmax/PV. T5: setprio around MFMA.
__global__ __launch_bounds__(256) void attn_kernel(
    const unsigned short* __restrict__ qkv,  // [MTOT][TD]; Q at h*64, K at 1024+h*64, V at 2048+h*64
    unsigned short* __restrict__ aout)       // [MTOT][DIM], col = h*64+d
{
    constexpr int KVB  = 64;
    constexpr int PADW = 72;
    __shared__ unsigned short Ks[KVB * PADW];       // [key][d]
    __shared__ unsigned short VsT[HD * PADW];       // [d][key]
    __shared__ unsigned short Plds[4 * 32 * PADW];  // per-wave [q(32)][key]

    const int t = threadIdx.x;
    const int l = t & 63;
    const int w = t >> 6;
    const int lrow = l & 15, lk = l >> 4;

    const int b  = blockIdx.y >> 4;
    const int h  = blockIdx.y & 15;
    const int q0 = blockIdx.x * 128 + w * 32;

    // Q fragments as B-operand, two q-sets (n = q = set*16 + lane&15)
    bf16x8 bq[2][2];
#pragma unroll
    for (int s = 0; s < 2; ++s) {
        const long qrow = (long)(b * SEQ + q0 + s * 16 + lrow) * TD + h * HD;
        bq[s][0] = *(const bf16x8*)&qkv[qrow + lk * 8];
        bq[s][1] = *(const bf16x8*)&qkv[qrow + 32 + lk * 8];
    }

    f32x4 o[2][4] = {};                  // O^T: lane q = set*16+lrow, d = 16*f2+4*lk+r
    float mrun[2] = { -1e30f, -1e30f };
    float lsum[2] = { 0.f, 0.f };

    const long kbase = (long)(b * SEQ) * TD + DIM + h * HD;
    const long vbase = (long)(b * SEQ) * TD + 2 * DIM + h * HD;

    // staging geometry: K -> thread loads row (t&63), 16B chunks at kc0, kc0+32
    //                   V -> thread loads rows 2*vrp, 2*vrp+1, d-chunk vch*8
    const int krow = t & 63, kc0 = (t >> 6) * 8;
    const int vch = t >> 5, vrp = t & 31;

    i32x4 kr0, kr1, vr0, vr1;  // prefetch registers (T14)

#define LOAD_TILE(m0) do {                                                     \
        const unsigned short* kp = &qkv[kbase + (long)((m0) + krow) * TD + kc0]; \
        kr0 = *(const i32x4*)kp;                                               \
        kr1 = *(const i32x4*)(kp + 32);                                        \
        const unsigned short* vp = &qkv[vbase + (long)((m0) + 2 * vrp) * TD + vch * 8]; \
        vr0 = *(const i32x4*)vp;                                               \
        vr1 = *(const i32x4*)(vp + TD);                                        \
    } while (0)

#define WRITE_TILE() do {                                                      \
        *(i32x4*)&Ks[krow * PADW + kc0]      = kr0;                            \
        *(i32x4*)&Ks[krow * PADW + kc0 + 32] = kr1;                            \
        const unsigned short* u0 = (const unsigned short*)&vr0;                \
        const unsigned short* u1 = (const unsigned short*)&vr1;                \
        unsigned int* V32 = (unsigned int*)VsT;                                \
        _Pragma("unroll")                                                      \
        for (int j = 0; j < 8; ++j) {                                          \
            unsigned int word = (unsigned int)u0[j] | ((unsigned int)u1[j] << 16); \
            V32[(vch * 8 + j) * 36 + vrp] = word;                              \
        }                                                                      \
    } while (0)

    unsigned short* P = &Plds[w * 32 * PADW];

    // prologue: stage tile 0
    LOAD_TILE(0);
    WRITE_TILE();
    __syncthreads();

    for (int m0 = 0; m0 < SEQ; m0 += KVB) {
        // ---- T14: issue next tile's global loads now (held in regs) ----
        const int mn = (m0 + KVB) & (SEQ - 1);   // wraps to 0 on last iter (write unused)
        LOAD_TILE(mn);

        // ---- QK^T swapped, both q-sets share the K fragments ----
        f32x4 sv[2][4];
        __builtin_amdgcn_s_setprio(1);
#pragma unroll
        for (int f = 0; f < 4; ++f) {
            bf16x8 ak0 = *(const bf16x8*)&Ks[(f * 16 + lrow) * PADW + lk * 8];
            bf16x8 ak1 = *(const bf16x8*)&Ks[(f * 16 + lrow) * PADW + 32 + lk * 8];
#pragma unroll
            for (int s = 0; s < 2; ++s) {
                f32x4 z = {};
                z = __builtin_amdgcn_mfma_f32_16x16x32_bf16(ak0, bq[s][0], z, 0, 0, 0);
                z = __builtin_amdgcn_mfma_f32_16x16x32_bf16(ak1, bq[s][1], z, 0, 0, 0);
                sv[s][f] = z;
            }
        }
        __builtin_amdgcn_s_setprio(0);

        // ---- online softmax (scores already in log2 domain) ----
        float vmax[2];
#pragma unroll
        for (int s = 0; s < 2; ++s) {
            float a0 = fmaxf(fmaxf(sv[s][0][0], sv[s][0][1]), fmaxf(sv[s][0][2], sv[s][0][3]));
            float a1 = fmaxf(fmaxf(sv[s][1][0], sv[s][1][1]), fmaxf(sv[s][1][2], sv[s][1][3]));
            float a2 = fmaxf(fmaxf(sv[s][2][0], sv[s][2][1]), fmaxf(sv[s][2][2], sv[s][2][3]));
            float a3 = fmaxf(fmaxf(sv[s][3][0], sv[s][3][1]), fmaxf(sv[s][3][2], sv[s][3][3]));
            float vm = fmaxf(fmaxf(a0, a1), fmaxf(a2, a3));
            vm = fmaxf(vm, __shfl_xor(vm, 16));
            vm = fmaxf(vm, __shfl_xor(vm, 32));
            vmax[s] = vm;
        }

        // T13 defer-max: rescale only when some lane's max grew past mrun+8
        if (!__all(vmax[0] <= mrun[0] + 8.f && vmax[1] <= mrun[1] + 8.f)) {
#pragma unroll
            for (int s = 0; s < 2; ++s) {
                float mnew = fmaxf(mrun[s], vmax[s]);
                float sc = exp2f(mrun[s] - mnew);
                mrun[s] = mnew;
                lsum[s] *= sc;
#pragma unroll
                for (int f2 = 0; f2 < 4; ++f2)
#pragma unroll
                    for (int r = 0; r < 4; ++r) o[s][f2][r] *= sc;
            }
        }

#pragma unroll
        for (int s = 0; s < 2; ++s) {
            float ps = 0.f;
#pragma unroll
            for (int f = 0; f < 4; ++f)
#pragma unroll
                for (int r = 0; r < 4; ++r) {
                    float p = exp2f(sv[s][f][r] - mrun[s]);
                    sv[s][f][r] = p;
                    ps += p;
                }
            ps += __shfl_xor(ps, 16);
            ps += __shfl_xor(ps, 32);
            lsum[s] += ps;
        }

        // ---- P -> LDS as [q][key] rows (wave-private), packed 32-bit writes ----
#pragma unroll
        for (int s = 0; s < 2; ++s)
#pragma unroll
            for (int f = 0; f < 4; ++f)
#pragma unroll
                for (int rr = 0; rr < 2; ++rr) {
                    ushort2 wd;
                    wd.x = f2bf(sv[s][f][2 * rr]);
                    wd.y = f2bf(sv[s][f][2 * rr + 1]);
                    *(ushort2*)&P[(s * 16 + lrow) * PADW + f * 16 + lk * 4 + 2 * rr] = wd;
                }

        // ---- PV transposed: O^T += V^T[d][k] * P^T[k][q], V frags shared ----
        bf16x8 pb[2][2];
#pragma unroll
        for (int s = 0; s < 2; ++s) {
            pb[s][0] = *(const bf16x8*)&P[(s * 16 + lrow) * PADW + lk * 8];
            pb[s][1] = *(const bf16x8*)&P[(s * 16 + lrow) * PADW + 32 + lk * 8];
        }
        __builtin_amdgcn_s_setprio(1);
#pragma unroll
        for (int f2 = 0; f2 < 4; ++f2) {
            bf16x8 av0 = *(const bf16x8*)&VsT[(f2 * 16 + lrow) * PADW + lk * 8];
            bf16x8 av1 = *(const bf16x8*)&VsT[(f2 * 16 + lrow) * PADW + 32 + lk * 8];
#pragma unroll
            for (int s = 0; s < 2; ++s) {
                o[s][f2] = __builtin_amdgcn_mfma_f32_16x16x32_bf16(av0, pb[s][0], o[s][f2], 0, 0, 0);
                o[s][f2] = __builtin_amdgcn_mfma_f32_16x16x32_bf16(av1, pb[s][1], o[s][f2], 0, 0, 0);
            }
        }
        __builtin_amdgcn_s_setprio(0);

        __syncthreads();   // all waves done reading Ks/VsT (tile t)
        WRITE_TILE();      // commit prefetched tile t+1 (vmcnt waits inserted here)
        __syncthreads();   // tile t+1 visible to all
    }

#undef LOAD_TILE
#undef WRITE_TILE

    // ---- normalize + store ----
#pragma unroll
    for (int s = 0; s < 2; ++s) {
        float inv = 1.0f / lsum[s];
        const long orow = (long)(b * SEQ + q0 + s * 16 + lrow);
#pragma unroll
        for (int f2 = 0; f2 < 4; ++f2) {
            ushort4 st;
            st.x = f2bf(o[s][f2][0] * inv);
            st.y = f2bf(o[s][f2][1] * inv);
            st.z = f2bf(o[s][f2][2] * inv);
            st.w = f2bf(o[s][f2][3] * inv);
            *(ushort4*)&aout[orow * DIM + h * HD + f2 * 16 + lk * 4] = st;
        }
    }
}

extern "C" void kernel_launch(void* const* d_in, const int* in_sizes, int n_in,
                              void* d_out, int out_size, void* d_ws, size_t ws_size,
                              hipStream_t stream)
{
    const float* x      = (const float*)d_in[0];
    const float* w_qkv  = (const float*)d_in[1];
    const float* b_qkv  = (const float*)d_in[2];
    const float* w_proj = (const float*)d_in[3];
    const float* b_proj = (const float*)d_in[4];
    float* out = (float*)d_out;

    unsigned short* x_bf   = (unsigned short*)d_ws;                 // 8192*1024
    unsigned short* wqkvT  = x_bf   + (size_t)MTOT * DIM;           // [3072][1024]
    unsigned short* wprojT = wqkvT  + (size_t)TD * DIM;             // [1024][1024]
    unsigned short* qkv    = wprojT + (size_t)DIM * DIM;            // [8192][3072]
    unsigned short* attn   = qkv    + (size_t)MTOT * TD;            // [8192][1024]

    cvt_kernel<<<2048, 256, 0, stream>>>(x, x_bf, MTOT * DIM / 4);
    dim3 tb(32, 8);
    transp_kernel<<<dim3(TD / 32, DIM / 32), tb, 0, stream>>>(w_qkv, wqkvT, DIM, TD);
    transp_kernel<<<dim3(DIM / 32, DIM / 32), tb, 0, stream>>>(w_proj, wprojT, DIM, DIM);

    // Q columns pre-scaled by 0.125*log2e (fp32, before bf16 round)
    gemm_bt_kernel<true><<<dim3(TD / 128, MTOT / 128), 256, 0, stream>>>(
        x_bf, wqkvT, b_qkv, qkv, MTOT, TD, DIM, DIM, QSCALE);

    attn_kernel<<<dim3(SEQ / 128, BATCH * NH), 256, 0, stream>>>(qkv, attn);

    gemm_bt_kernel<false><<<dim3(DIM / 128, MTOT / 128), 256, 0, stream>>>(
        attn, wprojT, b_proj, out, MTOT, DIM, DIM, 0, 1.0f);
}

// Round 5
// 237.606 us; speedup vs baseline: 1.2531x; 1.1044x over previous
//
#include <hip/hip_runtime.h>
#include <hip/hip_bf16.h>

#define DEVI __device__ __forceinline__

typedef float f32x4  __attribute__((ext_vector_type(4)));
typedef float f32x16 __attribute__((ext_vector_type(16)));
typedef short bf16x8 __attribute__((ext_vector_type(8)));
typedef int   i32x4  __attribute__((ext_vector_type(4)));

constexpr int BATCH = 4;
constexpr int SEQ   = 2048;
constexpr int DIM   = 1024;
constexpr int NH    = 16;
constexpr int HD    = 64;
constexpr int TD    = 3 * DIM;       // 3072
constexpr int MTOT  = BATCH * SEQ;   // 8192

// 1/sqrt(64) * log2(e), folded into Q at the QKV-GEMM epilogue.
constexpr float QSCALE = 0.125f * 1.44269504f;

DEVI unsigned short f2bf(float f) {
    __hip_bfloat16 h = __float2bfloat16(f);   // native cvt, RNE
    return *reinterpret_cast<unsigned short*>(&h);
}

DEVI void gload_lds16(const unsigned short* gsrc, unsigned short* ldst) {
    __builtin_amdgcn_global_load_lds(
        (const __attribute__((address_space(1))) void*)gsrc,
        (__attribute__((address_space(3))) void*)ldst,
        16, 0, 0);
}

// ---------------- convert f32 -> bf16 ----------------
__global__ void cvt_kernel(const float* __restrict__ in, unsigned short* __restrict__ out, int n4) {
    int i = blockIdx.x * blockDim.x + threadIdx.x;
    int stride = gridDim.x * blockDim.x;
    for (; i < n4; i += stride) {
        float4 v = reinterpret_cast<const float4*>(in)[i];
        ushort4 o;
        o.x = f2bf(v.x); o.y = f2bf(v.y); o.z = f2bf(v.z); o.w = f2bf(v.w);
        reinterpret_cast<ushort4*>(out)[i] = o;
    }
}

// ---------------- transpose f32 [R][C] -> bf16 [C][R] ----------------
__global__ void transp_kernel(const float* __restrict__ in, unsigned short* __restrict__ out, int R, int C) {
    __shared__ float tile[32][33];
    int c0 = blockIdx.x * 32, r0 = blockIdx.y * 32;
    int tx = threadIdx.x, ty = threadIdx.y;  // block 32x8
#pragma unroll
    for (int i = 0; i < 32; i += 8)
        tile[ty + i][tx] = in[(long)(r0 + ty + i) * C + c0 + tx];
    __syncthreads();
#pragma unroll
    for (int i = 0; i < 32; i += 8)
        out[(long)(c0 + ty + i) * R + r0 + tx] = f2bf(tile[tx][ty + i]);
}

// ---------------- GEMM: C[M][N] = A[M][K] * Bt[N][K]^T + bias ----------------
// m97 structure: 128x128 tile, BK=32, 4 waves (each 64x64), global_load_lds w=16.
// Columns [0, scale_ncols) of the output are multiplied by scl (fp32, pre-round).
template <bool OUT_BF16>
__global__ __launch_bounds__(256) void gemm_bt_kernel(
    const unsigned short* __restrict__ A,   // [M][K] bf16
    const unsigned short* __restrict__ Bt,  // [N][K] bf16
    const float* __restrict__ bias,         // [N]
    void* __restrict__ Cout,
    int M, int Nn, int K, int scale_ncols, float scl)
{
    __shared__ unsigned short As[128 * 32];
    __shared__ unsigned short Bs[128 * 32];

    const int t  = threadIdx.x;
    const int l  = t & 63;
    const int w  = t >> 6;
    const int wr = w >> 1, wc = w & 1;
    const int tr = blockIdx.y, tc = blockIdx.x;
    const int lrow = l & 15, lk = l >> 4;

    f32x4 acc[4][4] = {};

    const int r0  = t >> 2;
    const int ch0 = t & 3;
    const long arow_base = (long)(tr * 128) * K;
    const long brow_base = (long)(tc * 128) * K;

    const int nk = K >> 5;
    for (int kt = 0; kt < nk; ++kt) {
        const int kb = kt * 32;
        gload_lds16(A  + arow_base + (long)r0 * K        + kb + ch0 * 8, &As[t * 8]);
        gload_lds16(A  + arow_base + (long)(r0 + 64) * K + kb + ch0 * 8, &As[(t + 256) * 8]);
        gload_lds16(Bt + brow_base + (long)r0 * K        + kb + ch0 * 8, &Bs[t * 8]);
        gload_lds16(Bt + brow_base + (long)(r0 + 64) * K + kb + ch0 * 8, &Bs[(t + 256) * 8]);
        __syncthreads();

        bf16x8 a[4], bb[4];
#pragma unroll
        for (int mi = 0; mi < 4; ++mi)
            a[mi] = *(const bf16x8*)&As[(wr * 64 + mi * 16 + lrow) * 32 + lk * 8];
#pragma unroll
        for (int ni = 0; ni < 4; ++ni)
            bb[ni] = *(const bf16x8*)&Bs[(wc * 64 + ni * 16 + lrow) * 32 + lk * 8];
#pragma unroll
        for (int mi = 0; mi < 4; ++mi)
#pragma unroll
            for (int ni = 0; ni < 4; ++ni)
                acc[mi][ni] = __builtin_amdgcn_mfma_f32_16x16x32_bf16(a[mi], bb[ni], acc[mi][ni], 0, 0, 0);
        __syncthreads();
    }

    const int row_base = tr * 128 + wr * 64;
    const int col_base = tc * 128 + wc * 64;
    const float mult = (col_base < scale_ncols) ? scl : 1.0f;  // uniform per block (128 | DIM)
    float bv[4];
#pragma unroll
    for (int ni = 0; ni < 4; ++ni) bv[ni] = bias[col_base + ni * 16 + lrow];

#pragma unroll
    for (int mi = 0; mi < 4; ++mi)
#pragma unroll
        for (int ni = 0; ni < 4; ++ni)
#pragma unroll
            for (int r = 0; r < 4; ++r) {
                int row = row_base + mi * 16 + lk * 4 + r;
                int col = col_base + ni * 16 + lrow;
                float v = (acc[mi][ni][r] + bv[ni]) * mult;
                if (OUT_BF16) ((unsigned short*)Cout)[(long)row * Nn + col] = f2bf(v);
                else          ((float*)Cout)[(long)row * Nn + col] = v;
            }
}

// ---------------- fused flash attention (32x32 MFMA, in-register P) --------
// 4 waves x 32 q-rows = 128 q/block; KV tiles of 64. Swapped QK^T:
// S^T = mfma_32x32x16(K, Q) -> lane holds 32 P-values for q = lane&31; lanes
// l and l+32 hold complementary key subsets of the SAME q. P is converted
// with v_cvt_pk_bf16_f32 and redistributed with v_permlane32_swap_b32 (T12)
// straight into PV's B-operand -- no P LDS round-trip. T14 reg-prefetch of
// next K/V tile, T5 setprio, T13 defer-max retained.
__global__ __launch_bounds__(256, 2) void attn_kernel(
    const unsigned short* __restrict__ qkv,  // [MTOT][TD]; Q at h*64, K at 1024+h*64, V at 2048+h*64
    unsigned short* __restrict__ aout)       // [MTOT][DIM], col = h*64+d
{
    constexpr int KVB  = 64;
    constexpr int PADW = 72;
    __shared__ unsigned short Ks[KVB * PADW];   // [key][d]
    __shared__ unsigned short VsT[HD * PADW];   // [d][key]

    const int t = threadIdx.x;
    const int l = t & 63;
    const int w = t >> 6;
    const int ln = l & 31;     // q (and m-row for A-operands)
    const int hi = l >> 5;     // k-half selector

    const int b  = blockIdx.y >> 4;
    const int h  = blockIdx.y & 15;
    const int q0 = blockIdx.x * 128 + w * 32;

    // Q as B-operand: 4 k-slices of 16; lane holds Q[q=ln][d = s*16 + hi*8 + j]
    bf16x8 bq[4];
    {
        const long qrow = (long)(b * SEQ + q0 + ln) * TD + h * HD;
#pragma unroll
        for (int s = 0; s < 4; ++s)
            bq[s] = *(const bf16x8*)&qkv[qrow + s * 16 + hi * 8];
    }

    f32x16 o[2];   // O^T: d-blocks of 32; col q = ln, row d = (r&3)+8*(r>>2)+4*hi
#pragma unroll
    for (int i = 0; i < 16; ++i) { o[0][i] = 0.f; o[1][i] = 0.f; }
    float mrun = -1e30f, lsum = 0.f;

    const long kbase = (long)(b * SEQ) * TD + DIM + h * HD;
    const long vbase = (long)(b * SEQ) * TD + 2 * DIM + h * HD;

    // staging geometry: K -> thread loads row (t&63), 16B chunks at kc0, kc0+32
    //                   V -> thread loads rows 2*vrp, 2*vrp+1, d-chunk vch*8
    const int krow = t & 63, kc0 = (t >> 6) * 8;
    const int vch = t >> 5, vrp = t & 31;

    i32x4 kr0, kr1, vr0, vr1;  // prefetch registers (T14)

#define LOAD_TILE(m0) do {                                                     \
        const unsigned short* kp = &qkv[kbase + (long)((m0) + krow) * TD + kc0]; \
        kr0 = *(const i32x4*)kp;                                               \
        kr1 = *(const i32x4*)(kp + 32);                                        \
        const unsigned short* vp = &qkv[vbase + (long)((m0) + 2 * vrp) * TD + vch * 8]; \
        vr0 = *(const i32x4*)vp;                                               \
        vr1 = *(const i32x4*)(vp + TD);                                        \
    } while (0)

#define WRITE_TILE() do {                                                      \
        *(i32x4*)&Ks[krow * PADW + kc0]      = kr0;                            \
        *(i32x4*)&Ks[krow * PADW + kc0 + 32] = kr1;                            \
        const unsigned short* u0 = (const unsigned short*)&vr0;                \
        const unsigned short* u1 = (const unsigned short*)&vr1;                \
        unsigned int* V32 = (unsigned int*)VsT;                                \
        _Pragma("unroll")                                                      \
        for (int j = 0; j < 8; ++j) {                                          \
            unsigned int word = (unsigned int)u0[j] | ((unsigned int)u1[j] << 16); \
            V32[(vch * 8 + j) * 36 + vrp] = word;                              \
        }                                                                      \
    } while (0)

    // prologue: stage tile 0
    LOAD_TILE(0);
    WRITE_TILE();
    __syncthreads();

    for (int m0 = 0; m0 < SEQ; m0 += KVB) {
        // ---- T14: issue next tile's global loads now (held in regs) ----
        const int mn = (m0 + KVB) & (SEQ - 1);   // wraps to 0 on last iter (write unused)
        LOAD_TILE(mn);

        // ---- QK^T: S^T[key 64][q 32], 2 key-blocks x 4 d-slices ----
        f32x16 sv[2];
        __builtin_amdgcn_s_setprio(1);
#pragma unroll
        for (int f = 0; f < 2; ++f) {
            f32x16 acc = {};
#pragma unroll
            for (int s = 0; s < 4; ++s) {
                bf16x8 ak = *(const bf16x8*)&Ks[(f * 32 + ln) * PADW + s * 16 + hi * 8];
                acc = __builtin_amdgcn_mfma_f32_32x32x16_bf16(ak, bq[s], acc, 0, 0, 0);
            }
            sv[f] = acc;
        }
        __builtin_amdgcn_s_setprio(0);

        // ---- online softmax (scores in log2 domain; q = ln, shared by l^32) --
        float vm = sv[0][0];
#pragma unroll
        for (int i = 1; i < 16; ++i) vm = fmaxf(vm, sv[0][i]);
#pragma unroll
        for (int i = 0; i < 16; ++i) vm = fmaxf(vm, sv[1][i]);
        vm = fmaxf(vm, __shfl_xor(vm, 32));

        // T13 defer-max
        if (!__all(vm <= mrun + 8.f)) {
            float mnew = fmaxf(mrun, vm);
            float sc = exp2f(mrun - mnew);
            mrun = mnew;
            lsum *= sc;
#pragma unroll
            for (int f = 0; f < 2; ++f)
#pragma unroll
                for (int i = 0; i < 16; ++i) o[f][i] *= sc;
        }

        float ps = 0.f;
#pragma unroll
        for (int f = 0; f < 2; ++f)
#pragma unroll
            for (int i = 0; i < 16; ++i) {
                float p = exp2f(sv[f][i] - mrun);
                sv[f][i] = p;
                ps += p;
            }
        ps += __shfl_xor(ps, 32);
        lsum += ps;

        // ---- T12: P -> bf16 B-operand fragments in-register ----
        // slice ks (16 keys): keys ks*16 + hi*8 + j needed; own regs provide
        // half, partner lane (l^32) the other half via permlane32_swap.
        bf16x8 pb[4];
#pragma unroll
        for (int ks = 0; ks < 4; ++ks) {
            const int f = ks >> 1, base = (ks & 1) * 8;
            unsigned x0, x1, y0, y1;
            asm("v_cvt_pk_bf16_f32 %0, %1, %2" : "=v"(x0) : "v"(sv[f][base + 0]), "v"(sv[f][base + 1]));
            asm("v_cvt_pk_bf16_f32 %0, %1, %2" : "=v"(x1) : "v"(sv[f][base + 2]), "v"(sv[f][base + 3]));
            asm("v_cvt_pk_bf16_f32 %0, %1, %2" : "=v"(y0) : "v"(sv[f][base + 4]), "v"(sv[f][base + 5]));
            asm("v_cvt_pk_bf16_f32 %0, %1, %2" : "=v"(y1) : "v"(sv[f][base + 6]), "v"(sv[f][base + 7]));
            asm("v_permlane32_swap_b32 %0, %1" : "+v"(x0), "+v"(y0));
            asm("v_permlane32_swap_b32 %0, %1" : "+v"(x1), "+v"(y1));
            union { unsigned u[4]; bf16x8 v; } pu;
            pu.u[0] = x0; pu.u[1] = x1; pu.u[2] = y0; pu.u[3] = y1;
            pb[ks] = pu.v;
        }

        // ---- PV: O^T[d][q] += V^T[d][key] * P^T[key][q] ----
        __builtin_amdgcn_s_setprio(1);
#pragma unroll
        for (int f2 = 0; f2 < 2; ++f2)
#pragma unroll
            for (int ks = 0; ks < 4; ++ks) {
                bf16x8 av = *(const bf16x8*)&VsT[(f2 * 32 + ln) * PADW + ks * 16 + hi * 8];
                o[f2] = __builtin_amdgcn_mfma_f32_32x32x16_bf16(av, pb[ks], o[f2], 0, 0, 0);
            }
        __builtin_amdgcn_s_setprio(0);

        __syncthreads();   // all waves done reading Ks/VsT (tile t)
        WRITE_TILE();      // commit prefetched tile t+1 (vmcnt waits inserted here)
        __syncthreads();   // tile t+1 visible to all
    }

#undef LOAD_TILE
#undef WRITE_TILE

    // ---- normalize + store: reg r=4g+e -> d = e + 8g + 4hi (+32*f2) ----
    float inv = 1.0f / lsum;
    const long orow = (long)(b * SEQ + q0 + ln);
#pragma unroll
    for (int f2 = 0; f2 < 2; ++f2)
#pragma unroll
        for (int g = 0; g < 4; ++g) {
            ushort4 st;
            st.x = f2bf(o[f2][4 * g + 0] * inv);
            st.y = f2bf(o[f2][4 * g + 1] * inv);
            st.z = f2bf(o[f2][4 * g + 2] * inv);
            st.w = f2bf(o[f2][4 * g + 3] * inv);
            *(ushort4*)&aout[orow * DIM + h * HD + f2 * 32 + 8 * g + 4 * hi] = st;
        }
}

extern "C" void kernel_launch(void* const* d_in, const int* in_sizes, int n_in,
                              void* d_out, int out_size, void* d_ws, size_t ws_size,
                              hipStream_t stream)
{
    const float* x      = (const float*)d_in[0];
    const float* w_qkv  = (const float*)d_in[1];
    const float* b_qkv  = (const float*)d_in[2];
    const float* w_proj = (const float*)d_in[3];
    const float* b_proj = (const float*)d_in[4];
    float* out = (float*)d_out;

    unsigned short* x_bf   = (unsigned short*)d_ws;                 // 8192*1024
    unsigned short* wqkvT  = x_bf   + (size_t)MTOT * DIM;           // [3072][1024]
    unsigned short* wprojT = wqkvT  + (size_t)TD * DIM;             // [1024][1024]
    unsigned short* qkv    = wprojT + (size_t)DIM * DIM;            // [8192][3072]
    unsigned short* attn   = qkv    + (size_t)MTOT * TD;            // [8192][1024]

    cvt_kernel<<<2048, 256, 0, stream>>>(x, x_bf, MTOT * DIM / 4);
    dim3 tb(32, 8);
    transp_kernel<<<dim3(TD / 32, DIM / 32), tb, 0, stream>>>(w_qkv, wqkvT, DIM, TD);
    transp_kernel<<<dim3(DIM / 32, DIM / 32), tb, 0, stream>>>(w_proj, wprojT, DIM, DIM);

    // Q columns pre-scaled by 0.125*log2e (fp32, before bf16 round)
    gemm_bt_kernel<true><<<dim3(TD / 128, MTOT / 128), 256, 0, stream>>>(
        x_bf, wqkvT, b_qkv, qkv, MTOT, TD, DIM, DIM, QSCALE);

    attn_kernel<<<dim3(SEQ / 128, BATCH * NH), 256, 0, stream>>>(qkv, attn);

    gemm_bt_kernel<false><<<dim3(DIM / 128, MTOT / 128), 256, 0, stream>>>(
        attn, wprojT, b_proj, out, MTOT, DIM, DIM, 0, 1.0f);
}